// Round 14
// baseline (898.843 us; speedup 1.0000x reference)
//
#include <hip/hip_runtime.h>
#include <hip/hip_bf16.h>
#include <stdint.h>

// B=8, NW=1024, WL=8, CH=4, D=512, H=8, L=4, FF=2048, K=512, SCALE=0.125

#define NTOK 8192
#define DMODEL 512
#define NHEAD 8
#define DHEAD 64
#define NWIN 1024
#define NBATCH 8
#define KMASK 512
#define FFDIM 2048
#define NLAYER 4

typedef __bf16 bf16x8 __attribute__((ext_vector_type(8)));
typedef float f32x4 __attribute__((ext_vector_type(4)));

#define MFMA16(a, b, c) __builtin_amdgcn_mfma_f32_16x16x32_bf16(a, b, c, 0, 0, 0)

static __device__ __forceinline__ void gload_lds16(const void* g, void* l) {
    __builtin_amdgcn_global_load_lds(
        (const __attribute__((address_space(1))) uint32_t*)g,
        (__attribute__((address_space(3))) uint32_t*)l, 16, 0, 0);
}

// gelu tanh-approx, sigmoid form (mathematically identical, ~8 VALU vs tanhf ~25+)
static __device__ __forceinline__ float gelu_tanh(float v) {
    float u = 1.5957691216f * (v + 0.044715f * v * v * v);
    return v / (1.f + __expf(-u));
}

// ---------------------------------------------------------------------------
// Fused token embedding (fp32 in, fp32 out)
// ---------------------------------------------------------------------------
__global__ void embed_kernel(const float* __restrict__ seq,
                             const float* __restrict__ pos_emb,
                             const float* __restrict__ pln1_g,
                             const float* __restrict__ pln1_b,
                             const float* __restrict__ W_emb,
                             const float* __restrict__ b_emb,
                             const float* __restrict__ pln2_g,
                             const float* __restrict__ pln2_b,
                             float* __restrict__ x) {
    int tok = blockIdx.x;
    int w = tok & (NWIN - 1);
    int t = threadIdx.x;

    __shared__ float wraw[32];
    __shared__ float ln1[32];
    __shared__ float red[256], red2[256];

    if (t < 32) wraw[t] = seq[(size_t)tok * 32 + t];
    __syncthreads();

    float m = 0.f;
    for (int j = 0; j < 32; j++) m += wraw[j];
    m *= (1.f / 32.f);
    float v = 0.f;
    for (int j = 0; j < 32; j++) { float d = wraw[j] - m; v += d * d; }
    v *= (1.f / 32.f);
    float rs = rsqrtf(v + 1e-5f);
    if (t < 32) ln1[t] = (wraw[t] - m) * rs * pln1_g[t] + pln1_b[t];
    __syncthreads();

    int c0 = t, c1 = t + 256;
    float e0 = b_emb[c0];
    float e1 = b_emb[c1];
    for (int j = 0; j < 32; j++) {
        float a = ln1[j];
        e0 += a * W_emb[j * DMODEL + c0];
        e1 += a * W_emb[j * DMODEL + c1];
    }

    red[t] = e0 + e1;
    red2[t] = e0 * e0 + e1 * e1;
    __syncthreads();
    for (int o = 128; o > 0; o >>= 1) {
        if (t < o) { red[t] += red[t + o]; red2[t] += red2[t + o]; }
        __syncthreads();
    }
    float mean = red[0] * (1.f / 512.f);
    float var = red2[0] * (1.f / 512.f) - mean * mean;
    float rs2 = rsqrtf(var + 1e-5f);

    const float* pr = pos_emb + (size_t)(1 + w) * DMODEL;
    x[(size_t)tok * DMODEL + c0] =
        (e0 - mean) * rs2 * pln2_g[c0] + pln2_b[c0] + pr[c0];
    x[(size_t)tok * DMODEL + c1] =
        (e1 - mean) * rs2 * pln2_g[c1] + pln2_b[c1] + pr[c1];
}

// ---------------------------------------------------------------------------
__global__ void mask_scatter_kernel(const int* __restrict__ mask_idx,
                                    const float* __restrict__ mask_token,
                                    const float* __restrict__ pos_emb,
                                    float* __restrict__ x) {
    int bk = blockIdx.x;
    int b = bk >> 9;
    int k = bk & 511;
    int idx = mask_idx[b * KMASK + k];
    int t = threadIdx.x;
    float* row = x + (size_t)(b * NWIN + idx) * DMODEL;
    const float* pr = pos_emb + (size_t)(1 + idx) * DMODEL;
    row[t]       = mask_token[t]       + pr[t];
    row[t + 256] = mask_token[t + 256] + pr[t + 256];
}

// ---------------------------------------------------------------------------
// Row LayerNorm over 512, fp32 in -> bf16 out. Wave-shuffle reduction.
// ---------------------------------------------------------------------------
__global__ void ln_kernel(const float* __restrict__ in,
                          __hip_bfloat16* __restrict__ out,
                          const float* __restrict__ g,
                          const float* __restrict__ bb) {
    int row = blockIdx.x;
    int t = threadIdx.x;
    const float* r = in + (size_t)row * DMODEL;
    float v0 = r[t], v1 = r[t + 256];
    float s = v0 + v1, s2 = v0 * v0 + v1 * v1;
    for (int off = 1; off < 64; off <<= 1) {
        s  += __shfl_xor(s, off);
        s2 += __shfl_xor(s2, off);
    }
    __shared__ float ws[8];
    int wave = t >> 6, lane = t & 63;
    if (lane == 0) { ws[wave] = s; ws[4 + wave] = s2; }
    __syncthreads();
    float S  = ws[0] + ws[1] + ws[2] + ws[3];
    float S2 = ws[4] + ws[5] + ws[6] + ws[7];
    float mean = S * (1.f / 512.f);
    float var = S2 * (1.f / 512.f) - mean * mean;
    float rs = rsqrtf(var + 1e-5f);
    out[(size_t)row * DMODEL + t] =
        __float2bfloat16((v0 - mean) * rs * g[t] + bb[t]);
    out[(size_t)row * DMODEL + t + 256] =
        __float2bfloat16((v1 - mean) * rs * g[t + 256] + bb[t + 256]);
}

// ---------------------------------------------------------------------------
// Weight convert+transpose: W[K][N] fp32 -> Wt[N][K] bf16, layer = blockIdx.z
// ---------------------------------------------------------------------------
__global__ void wconv_kernel(const float* __restrict__ src,
                             __hip_bfloat16* __restrict__ dst,
                             int K, int N) {
    int l = blockIdx.z;
    src += (size_t)l * K * N;
    dst += (size_t)l * K * N;
    __shared__ float t[32][33];
    int n0 = blockIdx.x * 32, k0 = blockIdx.y * 32;
    int tx = threadIdx.x & 31, ty = threadIdx.x >> 5;
    for (int p = 0; p < 4; p++) {
        int k = k0 + ty + p * 8;
        t[ty + p * 8][tx] = src[(size_t)k * N + n0 + tx];
    }
    __syncthreads();
    for (int p = 0; p < 4; p++) {
        int n = n0 + ty + p * 8;
        dst[(size_t)n * K + k0 + tx] = __float2bfloat16(t[tx][ty + p * 8]);
    }
}

// ---------------------------------------------------------------------------
// epilogue stores (coalesced, from LDS transpose buffer)
// ---------------------------------------------------------------------------
static __device__ __forceinline__ void epi_store128(
        const float* Cs, int c, int m0, int n0, int N, int tid,
        const float* bias, const float* resid,
        float* Cf, __hip_bfloat16* Cb, int act) {
    int rl = tid >> 3;
    int cb = (tid & 7) * 16;
    int grow = m0 + c * 32 + rl;
    size_t base = (size_t)grow * N + n0 + cb;
    if (Cf) {
        for (int q = 0; q < 4; q++) {
            float4 v = *(const float4*)&Cs[rl * 132 + cb + q * 4];
            float vv[4] = {v.x, v.y, v.z, v.w};
            float4 ov;
            float* op = (float*)&ov;
            for (int e = 0; e < 4; e++) {
                float u = vv[e];
                if (bias) u += bias[n0 + cb + q * 4 + e];
                if (act == 1) u = gelu_tanh(u);
                if (resid) u += resid[base + q * 4 + e];
                op[e] = u;
            }
            *(float4*)&Cf[base + q * 4] = ov;
        }
    } else {
        for (int half = 0; half < 2; half++) {
            union { uint4 u; __hip_bfloat16 h[8]; } pk;
            for (int e = 0; e < 8; e++) {
                float u = Cs[rl * 132 + cb + half * 8 + e];
                if (bias) u += bias[n0 + cb + half * 8 + e];
                if (act == 1) u = gelu_tanh(u);
                pk.h[e] = __float2bfloat16(u);
            }
            *(uint4*)&Cb[base + half * 8] = pk.u;
        }
    }
}

static __device__ __forceinline__ void epi_store64(
        const float* Cs, int c, int m0, int n0, int N, int tid,
        const float* bias, const float* resid,
        float* Cf, __hip_bfloat16* Cb, int act) {
    int rl = tid >> 3;
    int cb = (tid & 7) * 8;
    int grow = m0 + c * 32 + rl;
    size_t base = (size_t)grow * N + n0 + cb;
    if (Cf) {
        for (int q = 0; q < 2; q++) {
            float4 v = *(const float4*)&Cs[rl * 68 + cb + q * 4];
            float vv[4] = {v.x, v.y, v.z, v.w};
            float4 ov;
            float* op = (float*)&ov;
            for (int e = 0; e < 4; e++) {
                float u = vv[e];
                if (bias) u += bias[n0 + cb + q * 4 + e];
                if (act == 1) u = gelu_tanh(u);
                if (resid) u += resid[base + q * 4 + e];
                op[e] = u;
            }
            *(float4*)&Cf[base + q * 4] = ov;
        }
    } else {
        union { uint4 u; __hip_bfloat16 h[8]; } pk;
        for (int e = 0; e < 8; e++) {
            float u = Cs[rl * 68 + cb + e];
            if (bias) u += bias[n0 + cb + e];
            if (act == 1) u = gelu_tanh(u);
            pk.h[e] = __float2bfloat16(u);
        }
        *(uint4*)&Cb[base] = pk.u;
    }
}

// ---------------------------------------------------------------------------
// MFMA GEMM 128x128, BK=32, double-buffered (unchanged from R13)
// ---------------------------------------------------------------------------
#define PUT128(ACC, II, JJ)                                             \
    do {                                                                \
        int rb_ = (II) * 16 + quad * 4;                                 \
        int cc_ = wc * 64 + (JJ) * 16 + l16;                            \
        Cs[(rb_ + 0) * 132 + cc_] = (ACC)[0];                           \
        Cs[(rb_ + 1) * 132 + cc_] = (ACC)[1];                           \
        Cs[(rb_ + 2) * 132 + cc_] = (ACC)[2];                           \
        Cs[(rb_ + 3) * 132 + cc_] = (ACC)[3];                           \
    } while (0)

#define CHUNK128(C, A00, A01, A02, A03, A10, A11, A12, A13)             \
    do {                                                                \
        __syncthreads();                                                \
        if (wr == ((C) >> 1)) {                                         \
            PUT128(A00, 0, 0); PUT128(A01, 0, 1);                       \
            PUT128(A02, 0, 2); PUT128(A03, 0, 3);                       \
            PUT128(A10, 1, 0); PUT128(A11, 1, 1);                       \
            PUT128(A12, 1, 2); PUT128(A13, 1, 3);                       \
        }                                                               \
        __syncthreads();                                                \
        epi_store128(Cs, (C), m0, n0, N, tid, bias, resid, Cf, Cb, act);\
    } while (0)

#define STAGE128(K0, BUF)                                               \
    do {                                                                \
        char* as_ = smem + (BUF) * 16384;                               \
        char* bs_ = as_ + 8192;                                         \
        _Pragma("unroll")                                               \
        for (int p_ = 0; p_ < 2; p_++) {                                \
            gload_lds16(Abase + (size_t)(p_ * 16) * (K * 2) + (K0) * 2, \
                        as_ + (wave * 2 + p_) * 1024);                  \
            gload_lds16(Bbase + (size_t)(p_ * 16) * (K * 2) + (K0) * 2, \
                        bs_ + (wave * 2 + p_) * 1024);                  \
        }                                                               \
    } while (0)

__global__ __launch_bounds__(256) void mfma_gemm_kernel(
        const __hip_bfloat16* __restrict__ A,
        const __hip_bfloat16* __restrict__ Bt,
        const float* __restrict__ bias,
        const float* __restrict__ resid,
        float* __restrict__ Cf,
        __hip_bfloat16* __restrict__ Cb,
        int N, int K, int act, int ntile) {
    __shared__ __align__(16) char smem[32768];
    float* Cs = (float*)smem;

    int tid = threadIdx.x;
    int wave = tid >> 6, lane = tid & 63;
    int quad = lane >> 4, l16 = lane & 15;
    int wr = wave >> 1, wc = wave & 1;

    int id = blockIdx.x;
    int slot = id >> 3;
    int mt = (id & 7) * 8 + slot / ntile;
    int nt = slot - (slot / ntile) * ntile;
    int m0 = mt * 128, n0 = nt * 128;

    f32x4 zero = {0.f, 0.f, 0.f, 0.f};
    f32x4 acc00 = zero, acc01 = zero, acc02 = zero, acc03 = zero;
    f32x4 acc10 = zero, acc11 = zero, acc12 = zero, acc13 = zero;
    f32x4 acc20 = zero, acc21 = zero, acc22 = zero, acc23 = zero;
    f32x4 acc30 = zero, acc31 = zero, acc32 = zero, acc33 = zero;

    int srow = lane >> 2;
    int schk = ((lane & 3) + (lane >> 4)) & 3;
    const char* Abase = (const char*)A +
        ((size_t)(m0 + wave * 32 + srow) * K + schk * 8) * 2;
    const char* Bbase = (const char*)Bt +
        ((size_t)(n0 + wave * 32 + srow) * K + schk * 8) * 2;
    int soff = l16 * 4 + ((quad - (l16 >> 2)) & 3);

    int nit = K >> 5;
    STAGE128(0, 0);
    for (int it = 0; it < nit; it++) {
        __syncthreads();
        if (it + 1 < nit) STAGE128((it + 1) << 5, (it + 1) & 1);

        const __hip_bfloat16* as =
            (const __hip_bfloat16*)(smem + (it & 1) * 16384);
        const __hip_bfloat16* bs = as + 4096;

        bf16x8 a0 = *(const bf16x8*)&as[(wr * 4 + 0) * 512 + soff * 8];
        bf16x8 a1 = *(const bf16x8*)&as[(wr * 4 + 1) * 512 + soff * 8];
        bf16x8 a2 = *(const bf16x8*)&as[(wr * 4 + 2) * 512 + soff * 8];
        bf16x8 a3 = *(const bf16x8*)&as[(wr * 4 + 3) * 512 + soff * 8];
        bf16x8 b0 = *(const bf16x8*)&bs[(wc * 4 + 0) * 512 + soff * 8];
        bf16x8 b1 = *(const bf16x8*)&bs[(wc * 4 + 1) * 512 + soff * 8];
        bf16x8 b2 = *(const bf16x8*)&bs[(wc * 4 + 2) * 512 + soff * 8];
        bf16x8 b3 = *(const bf16x8*)&bs[(wc * 4 + 3) * 512 + soff * 8];

        acc00 = MFMA16(a0, b0, acc00); acc01 = MFMA16(a0, b1, acc01);
        acc02 = MFMA16(a0, b2, acc02); acc03 = MFMA16(a0, b3, acc03);
        acc10 = MFMA16(a1, b0, acc10); acc11 = MFMA16(a1, b1, acc11);
        acc12 = MFMA16(a1, b2, acc12); acc13 = MFMA16(a1, b3, acc13);
        acc20 = MFMA16(a2, b0, acc20); acc21 = MFMA16(a2, b1, acc21);
        acc22 = MFMA16(a2, b2, acc22); acc23 = MFMA16(a2, b3, acc23);
        acc30 = MFMA16(a3, b0, acc30); acc31 = MFMA16(a3, b1, acc31);
        acc32 = MFMA16(a3, b2, acc32); acc33 = MFMA16(a3, b3, acc33);
    }

    CHUNK128(0, acc00, acc01, acc02, acc03, acc10, acc11, acc12, acc13);
    CHUNK128(1, acc20, acc21, acc22, acc23, acc30, acc31, acc32, acc33);
    CHUNK128(2, acc00, acc01, acc02, acc03, acc10, acc11, acc12, acc13);
    CHUNK128(3, acc20, acc21, acc22, acc23, acc30, acc31, acc32, acc33);
}

// ---------------------------------------------------------------------------
// MFMA GEMM 64x64 (N=512 outputs): grid 1024 = 4 blocks/CU (unchanged)
// ---------------------------------------------------------------------------
#define PUT64v2(ACC, JJ)                                                \
    do {                                                                \
        int rb_ = (wave & 1) * 16 + quad * 4;                           \
        int cc_ = (JJ) * 16 + l16;                                      \
        Cs[(rb_ + 0) * 68 + cc_] = (ACC)[0];                            \
        Cs[(rb_ + 1) * 68 + cc_] = (ACC)[1];                            \
        Cs[(rb_ + 2) * 68 + cc_] = (ACC)[2];                            \
        Cs[(rb_ + 3) * 68 + cc_] = (ACC)[3];                            \
    } while (0)

#define CHUNK64v2(C)                                                    \
    do {                                                                \
        __syncthreads();                                                \
        if ((wave >> 1) == (C)) {                                       \
            PUT64v2(acc0, 0); PUT64v2(acc1, 1);                         \
            PUT64v2(acc2, 2); PUT64v2(acc3, 3);                         \
        }                                                               \
        __syncthreads();                                                \
        epi_store64(Cs, (C), m0, n0, N, tid, bias, resid, Cf, Cb, act); \
    } while (0)

#define STAGE64v2(K0, BUF)                                              \
    do {                                                                \
        char* as_ = smem + (BUF) * 8192;                                \
        char* bs_ = as_ + 4096;                                         \
        gload_lds16(Abase + (K0) * 2, as_ + wave * 1024);               \
        gload_lds16(Bbase + (K0) * 2, bs_ + wave * 1024);               \
    } while (0)

__global__ __launch_bounds__(256) void mfma_gemm_64_kernel(
        const __hip_bfloat16* __restrict__ A,
        const __hip_bfloat16* __restrict__ Bt,
        const float* __restrict__ bias,
        const float* __restrict__ resid,
        float* __restrict__ Cf,
        __hip_bfloat16* __restrict__ Cb,
        int N, int K, int act, int ntile) {
    __shared__ __align__(16) char smem[16384];
    float* Cs = (float*)smem;

    int tid = threadIdx.x;
    int wave = tid >> 6, lane = tid & 63;
    int quad = lane >> 4, l16 = lane & 15;

    int id = blockIdx.x;
    int slot = id >> 3;
    int mt = (id & 7) * 16 + slot / ntile;
    int nt = slot - (slot / ntile) * ntile;
    int m0 = mt * 64, n0 = nt * 64;

    f32x4 zero = {0.f, 0.f, 0.f, 0.f};
    f32x4 acc0 = zero, acc1 = zero, acc2 = zero, acc3 = zero;

    int srow = lane >> 2;
    int schk = ((lane & 3) + (lane >> 4)) & 3;
    const char* Abase = (const char*)A +
        ((size_t)(m0 + wave * 16 + srow) * K + schk * 8) * 2;
    const char* Bbase = (const char*)Bt +
        ((size_t)(n0 + wave * 16 + srow) * K + schk * 8) * 2;
    int soff = l16 * 4 + ((quad - (l16 >> 2)) & 3);

    int nit = K >> 5;
    STAGE64v2(0, 0);
    for (int it = 0; it < nit; it++) {
        __syncthreads();
        if (it + 1 < nit) STAGE64v2((it + 1) << 5, (it + 1) & 1);

        const __hip_bfloat16* as =
            (const __hip_bfloat16*)(smem + (it & 1) * 8192);
        const __hip_bfloat16* bs = as + 2048;

        bf16x8 a0 = *(const bf16x8*)&as[wave * 512 + soff * 8];
        bf16x8 b0 = *(const bf16x8*)&bs[0 * 512 + soff * 8];
        bf16x8 b1 = *(const bf16x8*)&bs[1 * 512 + soff * 8];
        bf16x8 b2 = *(const bf16x8*)&bs[2 * 512 + soff * 8];
        bf16x8 b3 = *(const bf16x8*)&bs[3 * 512 + soff * 8];

        acc0 = MFMA16(a0, b0, acc0); acc1 = MFMA16(a0, b1, acc1);
        acc2 = MFMA16(a0, b2, acc2); acc3 = MFMA16(a0, b3, acc3);
    }

    CHUNK64v2(0);
    CHUNK64v2(1);
}

// ---------------------------------------------------------------------------
// MFMA flash attention, SPLIT-K: each block does 128 queries x 512 keys
// (half the key range). Sum-only softmax => partials combine by addition.
// Writes unnormalized O (bf16) and row-sums l (f32); combine normalizes.
// grid 1024 = 4 blocks/CU.
// ---------------------------------------------------------------------------
#define KP 72
__global__ __launch_bounds__(256) void attn_mfma_kernel(
        const __hip_bfloat16* __restrict__ qkv,
        __hip_bfloat16* __restrict__ opart,
        float* __restrict__ lpart) {
    int id = blockIdx.x;
    int slot = id >> 3;                       // 0..127
    int bh = (id & 7) * 8 + (slot >> 4);      // all blocks of a (b,h) share XCD
    int itile = (slot >> 1) & 7;
    int split = slot & 1;
    int b = bh >> 3, hh = bh & 7;

    int tid = threadIdx.x;
    int wave = tid >> 6, lane = tid & 63;
    int quad = lane >> 4, l16 = lane & 15;
    int i0 = itile * 128;

    __shared__ __align__(16) __hip_bfloat16 Ks[64 * KP];
    __shared__ __align__(16) __hip_bfloat16 Vt[64 * KP];
    __shared__ __align__(16) __hip_bfloat16 Ps[4][16 * KP];

    bf16x8 aq[2][2];
#pragma unroll
    for (int g = 0; g < 2; g++) {
        const __hip_bfloat16* qrow =
            qkv + (size_t)(b * NWIN + i0 + g * 64 + wave * 16 + l16) * 1536 + hh * 64;
        aq[g][0] = *(const bf16x8*)(qrow + quad * 8);
        aq[g][1] = *(const bf16x8*)(qrow + 32 + quad * 8);
    }

    float lp[2][4];
    f32x4 acc[2][4];
    f32x4 zero = {0.f, 0.f, 0.f, 0.f};
#pragma unroll
    for (int g = 0; g < 2; g++)
#pragma unroll
        for (int n = 0; n < 4; n++) { acc[g][n] = zero; lp[g][n] = 0.f; }

    for (int kt = split * 8; kt < split * 8 + 8; kt++) {
        int k0 = kt * 64;
        __syncthreads();

#pragma unroll
        for (int p = 0; p < 2; p++) {
            int f = p * 256 + tid;
            int r = f >> 3;
            int j = f & 7;
            int c8 = j * 8;
            const __hip_bfloat16* kp =
                qkv + (size_t)(b * NWIN + k0 + r) * 1536 + 512 + hh * 64 + c8;
            *(uint4*)&Ks[r * KP + c8] = *(const uint4*)kp;
            union { uint4 u; __hip_bfloat16 h[8]; } vv;
            vv.u = *(const uint4*)(qkv + (size_t)(b * NWIN + k0 + r) * 1536 +
                                   1024 + hh * 64 + c8);
            int colb = (((r >> 3) ^ j) << 3) + (r & 7);
#pragma unroll
            for (int u = 0; u < 8; u++) Vt[(c8 + u) * KP + colb] = vv.h[u];
        }
        __syncthreads();

        bf16x8 bk[4][2], bv[4][2];
#pragma unroll
        for (int n = 0; n < 4; n++) {
            int key = n * 16 + l16;
            bk[n][0] = *(const bf16x8*)&Ks[key * KP + quad * 8];
            bk[n][1] = *(const bf16x8*)&Ks[key * KP + 32 + quad * 8];
            int d = n * 16 + l16;
            int sw = (d >> 3) & 7;
            bv[n][0] = *(const bf16x8*)&Vt[d * KP + ((quad ^ sw) << 3)];
            bv[n][1] = *(const bf16x8*)&Vt[d * KP + (((quad + 4) ^ sw) << 3)];
        }

#pragma unroll
        for (int g = 0; g < 2; g++) {
            f32x4 s[4];
#pragma unroll
            for (int n = 0; n < 4; n++) {
                f32x4 t = zero;
                t = MFMA16(aq[g][0], bk[n][0], t);
                t = MFMA16(aq[g][1], bk[n][1], t);
                s[n] = t;
            }
#pragma unroll
            for (int r = 0; r < 4; r++) {
                float ls = 0.f;
#pragma unroll
                for (int n = 0; n < 4; n++) {
                    float pv = __expf(s[n][r] * 0.125f);
                    Ps[wave][(quad * 4 + r) * KP + n * 16 + l16] =
                        __float2bfloat16(pv);
                    ls += pv;
                }
                lp[g][r] += ls;
            }
            bf16x8 ap0 = *(const bf16x8*)&Ps[wave][l16 * KP + quad * 8];
            bf16x8 ap1 = *(const bf16x8*)&Ps[wave][l16 * KP + 32 + quad * 8];
#pragma unroll
            for (int n = 0; n < 4; n++) {
                acc[g][n] = MFMA16(ap0, bv[n][0], acc[g][n]);
                acc[g][n] = MFMA16(ap1, bv[n][1], acc[g][n]);
            }
        }
    }

    // epilogue: reduce row sums, store unnormalized partials
#pragma unroll
    for (int g = 0; g < 2; g++) {
#pragma unroll
        for (int r = 0; r < 4; r++) {
            float ls = lp[g][r];
            ls += __shfl_xor(ls, 1);
            ls += __shfl_xor(ls, 2);
            ls += __shfl_xor(ls, 4);
            ls += __shfl_xor(ls, 8);
            int row = i0 + g * 64 + wave * 16 + quad * 4 + r;
            size_t tok = (size_t)(b * NWIN + row);
            if (l16 == 0)
                lpart[(size_t)split * NTOK * NHEAD + tok * NHEAD + hh] = ls;
#pragma unroll
            for (int n = 0; n < 4; n++) {
                opart[(size_t)split * NTOK * DMODEL + tok * DMODEL +
                      hh * 64 + n * 16 + l16] = __float2bfloat16(acc[g][n][r]);
            }
        }
    }
}

// ---------------------------------------------------------------------------
// Split-K combine: o = (O0 + O1) / (l0 + l1), bf16 out (in-place over opart1)
// ---------------------------------------------------------------------------
__global__ void attn_combine_kernel(const __hip_bfloat16* __restrict__ opart,
                                    const float* __restrict__ lpart,
                                    __hip_bfloat16* __restrict__ o) {
    size_t tok = blockIdx.x;
    int t = threadIdx.x;
    for (int half = 0; half < 2; half++) {
        int d = t + half * 256;
        int hh = d >> 6;
        float l0 = lpart[tok * NHEAD + hh];
        float l1 = lpart[(size_t)NTOK * NHEAD + tok * NHEAD + hh];
        float o0 = __bfloat162float(opart[tok * DMODEL + d]);
        float o1 = __bfloat162float(opart[(size_t)NTOK * DMODEL + tok * DMODEL + d]);
        o[tok * DMODEL + d] = __float2bfloat16((o0 + o1) / (l0 + l1));
    }
}

// ---------------------------------------------------------------------------
// Output head (fp32)
// ---------------------------------------------------------------------------
__global__ void out_kernel(const float* __restrict__ x,
                           const int* __restrict__ mask_idx,
                           const float* __restrict__ oln_g,
                           const float* __restrict__ oln_b,
                           const float* __restrict__ W_words,
                           const float* __restrict__ b_words,
                           const float* __restrict__ seq,
                           float* __restrict__ out) {
    int k = blockIdx.x, b = blockIdx.y;
    int idx = mask_idx[b * KMASK + k];
    int t = threadIdx.x;
    const float* row = x + (size_t)(b * NWIN + idx) * DMODEL;
    float v0 = row[t], v1 = row[t + 256];

    __shared__ float red[256], red2[256];
    __shared__ float sh[512];
    __shared__ float part[256];
    __shared__ float lg[32];

    red[t] = v0 + v1;
    red2[t] = v0 * v0 + v1 * v1;
    __syncthreads();
    for (int o = 128; o > 0; o >>= 1) {
        if (t < o) { red[t] += red[t + o]; red2[t] += red2[t + o]; }
        __syncthreads();
    }
    float mean = red[0] * (1.f / 512.f);
    float var = red2[0] * (1.f / 512.f) - mean * mean;
    float rs = rsqrtf(var + 1e-5f);
    sh[t]       = (v0 - mean) * rs * oln_g[t] + oln_b[t];
    sh[t + 256] = (v1 - mean) * rs * oln_g[t + 256] + oln_b[t + 256];
    __syncthreads();

    int c = t & 31, ch = t >> 5;
    float p = 0.f;
    for (int j = ch * 64; j < ch * 64 + 64; j++)
        p += sh[j] * W_words[j * 32 + c];
    part[t] = p;
    __syncthreads();
    if (t < 32) {
        float s = b_words[t];
        for (int u = 0; u < 8; u++) s += part[u * 32 + t];
        lg[t] = s;
    }
    __syncthreads();

    size_t obase = (size_t)(b * KMASK + k) * 32;
    if (t < 32) {
        int g0 = t & ~3;
        float mx = fmaxf(fmaxf(lg[g0], lg[g0 + 1]), fmaxf(lg[g0 + 2], lg[g0 + 3]));
        float s = expf(lg[g0] - mx) + expf(lg[g0 + 1] - mx) +
                  expf(lg[g0 + 2] - mx) + expf(lg[g0 + 3] - mx);
        out[obase + t] = expf(lg[t] - mx) / s;
        out[131072 + obase + t] = seq[(size_t)b * 32768 + (size_t)idx * 32 + t];
    }
}

// ---------------------------------------------------------------------------
extern "C" void kernel_launch(void* const* d_in, const int* in_sizes, int n_in,
                              void* d_out, int out_size, void* d_ws, size_t ws_size,
                              hipStream_t stream) {
    const float* seq      = (const float*)d_in[0];
    const int*   mask_idx = (const int*)d_in[1];
    const float* pos_emb  = (const float*)d_in[2];
    const float* mask_tok = (const float*)d_in[3];
    const float* pln1_g   = (const float*)d_in[4];
    const float* pln1_b   = (const float*)d_in[5];
    const float* W_emb    = (const float*)d_in[6];
    const float* b_emb    = (const float*)d_in[7];
    const float* pln2_g   = (const float*)d_in[8];
    const float* pln2_b   = (const float*)d_in[9];
    const float* aln_g    = (const float*)d_in[10];
    const float* aln_b    = (const float*)d_in[11];
    const float* Wqkv     = (const float*)d_in[12];
    const float* Wo       = (const float*)d_in[13];
    const float* fln_g    = (const float*)d_in[14];
    const float* fln_b    = (const float*)d_in[15];
    const float* Wff1     = (const float*)d_in[16];
    const float* bff1     = (const float*)d_in[17];
    const float* Wff2     = (const float*)d_in[18];
    const float* bff2     = (const float*)d_in[19];
    const float* oln_g    = (const float*)d_in[20];
    const float* oln_b    = (const float*)d_in[21];
    const float* W_words  = (const float*)d_in[22];
    const float* b_words  = (const float*)d_in[23];

    // ws layout (bytes):
    //   x fp32            [0, 16M)
    //   qkv_bf [16M,41.2M) / ff_bf [16M,48M)  (qkv dead before ff written)
    //   lpart  [44M, 44.5M)  (free slack; dead before ff written)
    //   opart  [48M, 64M)    = h_bf region (split0) + o_bf region (split1);
    //                          combine writes final o in-place over split1
    //   h_bf   [48M, 56M), o_bf [56M, 64M)
    //   weights bf16 [N][K]   [64M, ~89.2M)
    uint8_t* ws = (uint8_t*)d_ws;
    float* x = (float*)ws;
    __hip_bfloat16* qkv_bf = (__hip_bfloat16*)(ws + 16777216);
    __hip_bfloat16* ff_bf  = qkv_bf;
    float* lpart           = (float*)(ws + 46137344);
    __hip_bfloat16* opart  = (__hip_bfloat16*)(ws + 50331648);
    __hip_bfloat16* h_bf   = (__hip_bfloat16*)(ws + 50331648);
    __hip_bfloat16* o_bf   = (__hip_bfloat16*)(ws + 58720256);
    __hip_bfloat16* wqkv_t = (__hip_bfloat16*)(ws + 67108864);
    __hip_bfloat16* wo_t   = wqkv_t + (size_t)NLAYER * DMODEL * 3 * DMODEL;
    __hip_bfloat16* wff1_t = wo_t   + (size_t)NLAYER * DMODEL * DMODEL;
    __hip_bfloat16* wff2_t = wff1_t + (size_t)NLAYER * DMODEL * FFDIM;

    wconv_kernel<<<dim3(48, 16, NLAYER), 256, 0, stream>>>(Wqkv, wqkv_t, DMODEL, 3 * DMODEL);
    wconv_kernel<<<dim3(16, 16, NLAYER), 256, 0, stream>>>(Wo,   wo_t,   DMODEL, DMODEL);
    wconv_kernel<<<dim3(64, 16, NLAYER), 256, 0, stream>>>(Wff1, wff1_t, DMODEL, FFDIM);
    wconv_kernel<<<dim3(16, 64, NLAYER), 256, 0, stream>>>(Wff2, wff2_t, FFDIM, DMODEL);

    embed_kernel<<<NTOK, 256, 0, stream>>>(seq, pos_emb, pln1_g, pln1_b,
                                           W_emb, b_emb, pln2_g, pln2_b, x);
    mask_scatter_kernel<<<NBATCH * KMASK, 256, 0, stream>>>(mask_idx, mask_tok, pos_emb, x);

    for (int l = 0; l < NLAYER; l++) {
        ln_kernel<<<NTOK, 256, 0, stream>>>(x, h_bf, aln_g + l * DMODEL, aln_b + l * DMODEL);
        mfma_gemm_kernel<<<64 * 12, 256, 0, stream>>>(
            h_bf, wqkv_t + (size_t)l * DMODEL * 3 * DMODEL,
            nullptr, nullptr, nullptr, qkv_bf, 3 * DMODEL, DMODEL, 0, 12);
        attn_mfma_kernel<<<1024, 256, 0, stream>>>(qkv_bf, opart, lpart);
        attn_combine_kernel<<<NTOK, 256, 0, stream>>>(opart, lpart, o_bf);
        mfma_gemm_64_kernel<<<128 * 8, 256, 0, stream>>>(
            o_bf, wo_t + (size_t)l * DMODEL * DMODEL,
            nullptr, x, x, nullptr, DMODEL, DMODEL, 0, 8);
        ln_kernel<<<NTOK, 256, 0, stream>>>(x, h_bf, fln_g + l * DMODEL, fln_b + l * DMODEL);
        mfma_gemm_kernel<<<64 * 16, 256, 0, stream>>>(
            h_bf, wff1_t + (size_t)l * DMODEL * FFDIM,
            bff1 + (size_t)l * FFDIM, nullptr, nullptr, ff_bf, FFDIM, DMODEL, 1, 16);
        mfma_gemm_64_kernel<<<128 * 8, 256, 0, stream>>>(
            ff_bf, wff2_t + (size_t)l * FFDIM * DMODEL,
            bff2 + (size_t)l * DMODEL, x, x, nullptr, DMODEL, FFDIM, 0, 8);
    }

    out_kernel<<<dim3(KMASK, NBATCH), 256, 0, stream>>>(
        x, mask_idx, oln_g, oln_b, W_words, b_words, seq, (float*)d_out);
}

// Round 15
// 865.281 us; speedup vs baseline: 1.0388x; 1.0388x over previous
//
#include <hip/hip_runtime.h>
#include <hip/hip_bf16.h>
#include <stdint.h>

// B=8, NW=1024, WL=8, CH=4, D=512, H=8, L=4, FF=2048, K=512, SCALE=0.125

#define NTOK 8192
#define DMODEL 512
#define NHEAD 8
#define DHEAD 64
#define NWIN 1024
#define NBATCH 8
#define KMASK 512
#define FFDIM 2048
#define NLAYER 4

typedef __bf16 bf16x8 __attribute__((ext_vector_type(8)));
typedef float f32x4 __attribute__((ext_vector_type(4)));

#define MFMA16(a, b, c) __builtin_amdgcn_mfma_f32_16x16x32_bf16(a, b, c, 0, 0, 0)

static __device__ __forceinline__ void gload_lds16(const void* g, void* l) {
    __builtin_amdgcn_global_load_lds(
        (const __attribute__((address_space(1))) uint32_t*)g,
        (__attribute__((address_space(3))) uint32_t*)l, 16, 0, 0);
}

// gelu tanh-approx, sigmoid form (mathematically identical, ~8 VALU vs tanhf ~25+)
static __device__ __forceinline__ float gelu_tanh(float v) {
    float u = 1.5957691216f * (v + 0.044715f * v * v * v);
    return v / (1.f + __expf(-u));
}

// ---------------------------------------------------------------------------
// Fused token embedding (fp32 in, fp32 out)
// ---------------------------------------------------------------------------
__global__ void embed_kernel(const float* __restrict__ seq,
                             const float* __restrict__ pos_emb,
                             const float* __restrict__ pln1_g,
                             const float* __restrict__ pln1_b,
                             const float* __restrict__ W_emb,
                             const float* __restrict__ b_emb,
                             const float* __restrict__ pln2_g,
                             const float* __restrict__ pln2_b,
                             float* __restrict__ x) {
    int tok = blockIdx.x;
    int w = tok & (NWIN - 1);
    int t = threadIdx.x;

    __shared__ float wraw[32];
    __shared__ float ln1[32];
    __shared__ float red[256], red2[256];

    if (t < 32) wraw[t] = seq[(size_t)tok * 32 + t];
    __syncthreads();

    float m = 0.f;
    for (int j = 0; j < 32; j++) m += wraw[j];
    m *= (1.f / 32.f);
    float v = 0.f;
    for (int j = 0; j < 32; j++) { float d = wraw[j] - m; v += d * d; }
    v *= (1.f / 32.f);
    float rs = rsqrtf(v + 1e-5f);
    if (t < 32) ln1[t] = (wraw[t] - m) * rs * pln1_g[t] + pln1_b[t];
    __syncthreads();

    int c0 = t, c1 = t + 256;
    float e0 = b_emb[c0];
    float e1 = b_emb[c1];
    for (int j = 0; j < 32; j++) {
        float a = ln1[j];
        e0 += a * W_emb[j * DMODEL + c0];
        e1 += a * W_emb[j * DMODEL + c1];
    }

    red[t] = e0 + e1;
    red2[t] = e0 * e0 + e1 * e1;
    __syncthreads();
    for (int o = 128; o > 0; o >>= 1) {
        if (t < o) { red[t] += red[t + o]; red2[t] += red2[t + o]; }
        __syncthreads();
    }
    float mean = red[0] * (1.f / 512.f);
    float var = red2[0] * (1.f / 512.f) - mean * mean;
    float rs2 = rsqrtf(var + 1e-5f);

    const float* pr = pos_emb + (size_t)(1 + w) * DMODEL;
    x[(size_t)tok * DMODEL + c0] =
        (e0 - mean) * rs2 * pln2_g[c0] + pln2_b[c0] + pr[c0];
    x[(size_t)tok * DMODEL + c1] =
        (e1 - mean) * rs2 * pln2_g[c1] + pln2_b[c1] + pr[c1];
}

// ---------------------------------------------------------------------------
__global__ void mask_scatter_kernel(const int* __restrict__ mask_idx,
                                    const float* __restrict__ mask_token,
                                    const float* __restrict__ pos_emb,
                                    float* __restrict__ x) {
    int bk = blockIdx.x;
    int b = bk >> 9;
    int k = bk & 511;
    int idx = mask_idx[b * KMASK + k];
    int t = threadIdx.x;
    float* row = x + (size_t)(b * NWIN + idx) * DMODEL;
    const float* pr = pos_emb + (size_t)(1 + idx) * DMODEL;
    row[t]       = mask_token[t]       + pr[t];
    row[t + 256] = mask_token[t + 256] + pr[t + 256];
}

// ---------------------------------------------------------------------------
// Row LayerNorm over 512, fp32 in -> bf16 out. Wave-shuffle reduction.
// ---------------------------------------------------------------------------
__global__ void ln_kernel(const float* __restrict__ in,
                          __hip_bfloat16* __restrict__ out,
                          const float* __restrict__ g,
                          const float* __restrict__ bb) {
    int row = blockIdx.x;
    int t = threadIdx.x;
    const float* r = in + (size_t)row * DMODEL;
    float v0 = r[t], v1 = r[t + 256];
    float s = v0 + v1, s2 = v0 * v0 + v1 * v1;
    for (int off = 1; off < 64; off <<= 1) {
        s  += __shfl_xor(s, off);
        s2 += __shfl_xor(s2, off);
    }
    __shared__ float ws[8];
    int wave = t >> 6, lane = t & 63;
    if (lane == 0) { ws[wave] = s; ws[4 + wave] = s2; }
    __syncthreads();
    float S  = ws[0] + ws[1] + ws[2] + ws[3];
    float S2 = ws[4] + ws[5] + ws[6] + ws[7];
    float mean = S * (1.f / 512.f);
    float var = S2 * (1.f / 512.f) - mean * mean;
    float rs = rsqrtf(var + 1e-5f);
    out[(size_t)row * DMODEL + t] =
        __float2bfloat16((v0 - mean) * rs * g[t] + bb[t]);
    out[(size_t)row * DMODEL + t + 256] =
        __float2bfloat16((v1 - mean) * rs * g[t + 256] + bb[t + 256]);
}

// ---------------------------------------------------------------------------
// Weight convert+transpose: W[K][N] fp32 -> Wt[N][K] bf16, layer = blockIdx.z
// ---------------------------------------------------------------------------
__global__ void wconv_kernel(const float* __restrict__ src,
                             __hip_bfloat16* __restrict__ dst,
                             int K, int N) {
    int l = blockIdx.z;
    src += (size_t)l * K * N;
    dst += (size_t)l * K * N;
    __shared__ float t[32][33];
    int n0 = blockIdx.x * 32, k0 = blockIdx.y * 32;
    int tx = threadIdx.x & 31, ty = threadIdx.x >> 5;
    for (int p = 0; p < 4; p++) {
        int k = k0 + ty + p * 8;
        t[ty + p * 8][tx] = src[(size_t)k * N + n0 + tx];
    }
    __syncthreads();
    for (int p = 0; p < 4; p++) {
        int n = n0 + ty + p * 8;
        dst[(size_t)n * K + k0 + tx] = __float2bfloat16(t[tx][ty + p * 8]);
    }
}

// ---------------------------------------------------------------------------
// epilogue stores (coalesced, from LDS transpose buffer)
// ---------------------------------------------------------------------------
static __device__ __forceinline__ void epi_store128(
        const float* Cs, int c, int m0, int n0, int N, int tid,
        const float* bias, const float* resid,
        float* Cf, __hip_bfloat16* Cb, int act) {
    int rl = tid >> 3;
    int cb = (tid & 7) * 16;
    int grow = m0 + c * 32 + rl;
    size_t base = (size_t)grow * N + n0 + cb;
    if (Cf) {
        for (int q = 0; q < 4; q++) {
            float4 v = *(const float4*)&Cs[rl * 132 + cb + q * 4];
            float vv[4] = {v.x, v.y, v.z, v.w};
            float4 ov;
            float* op = (float*)&ov;
            for (int e = 0; e < 4; e++) {
                float u = vv[e];
                if (bias) u += bias[n0 + cb + q * 4 + e];
                if (act == 1) u = gelu_tanh(u);
                if (resid) u += resid[base + q * 4 + e];
                op[e] = u;
            }
            *(float4*)&Cf[base + q * 4] = ov;
        }
    } else {
        for (int half = 0; half < 2; half++) {
            union { uint4 u; __hip_bfloat16 h[8]; } pk;
            for (int e = 0; e < 8; e++) {
                float u = Cs[rl * 132 + cb + half * 8 + e];
                if (bias) u += bias[n0 + cb + half * 8 + e];
                if (act == 1) u = gelu_tanh(u);
                pk.h[e] = __float2bfloat16(u);
            }
            *(uint4*)&Cb[base + half * 8] = pk.u;
        }
    }
}

static __device__ __forceinline__ void epi_store64(
        const float* Cs, int c, int m0, int n0, int N, int tid,
        const float* bias, const float* resid,
        float* Cf, __hip_bfloat16* Cb, int act) {
    int rl = tid >> 3;
    int cb = (tid & 7) * 8;
    int grow = m0 + c * 32 + rl;
    size_t base = (size_t)grow * N + n0 + cb;
    if (Cf) {
        for (int q = 0; q < 2; q++) {
            float4 v = *(const float4*)&Cs[rl * 68 + cb + q * 4];
            float vv[4] = {v.x, v.y, v.z, v.w};
            float4 ov;
            float* op = (float*)&ov;
            for (int e = 0; e < 4; e++) {
                float u = vv[e];
                if (bias) u += bias[n0 + cb + q * 4 + e];
                if (act == 1) u = gelu_tanh(u);
                if (resid) u += resid[base + q * 4 + e];
                op[e] = u;
            }
            *(float4*)&Cf[base + q * 4] = ov;
        }
    } else {
        union { uint4 u; __hip_bfloat16 h[8]; } pk;
        for (int e = 0; e < 8; e++) {
            float u = Cs[rl * 68 + cb + e];
            if (bias) u += bias[n0 + cb + e];
            if (act == 1) u = gelu_tanh(u);
            pk.h[e] = __float2bfloat16(u);
        }
        *(uint4*)&Cb[base] = pk.u;
    }
}

// ---------------------------------------------------------------------------
// MFMA GEMM 128x128, BK=32, double-buffered
// ---------------------------------------------------------------------------
#define PUT128(ACC, II, JJ)                                             \
    do {                                                                \
        int rb_ = (II) * 16 + quad * 4;                                 \
        int cc_ = wc * 64 + (JJ) * 16 + l16;                            \
        Cs[(rb_ + 0) * 132 + cc_] = (ACC)[0];                           \
        Cs[(rb_ + 1) * 132 + cc_] = (ACC)[1];                           \
        Cs[(rb_ + 2) * 132 + cc_] = (ACC)[2];                           \
        Cs[(rb_ + 3) * 132 + cc_] = (ACC)[3];                           \
    } while (0)

#define CHUNK128(C, A00, A01, A02, A03, A10, A11, A12, A13)             \
    do {                                                                \
        __syncthreads();                                                \
        if (wr == ((C) >> 1)) {                                         \
            PUT128(A00, 0, 0); PUT128(A01, 0, 1);                       \
            PUT128(A02, 0, 2); PUT128(A03, 0, 3);                       \
            PUT128(A10, 1, 0); PUT128(A11, 1, 1);                       \
            PUT128(A12, 1, 2); PUT128(A13, 1, 3);                       \
        }                                                               \
        __syncthreads();                                                \
        epi_store128(Cs, (C), m0, n0, N, tid, bias, resid, Cf, Cb, act);\
    } while (0)

#define STAGE128(K0, BUF)                                               \
    do {                                                                \
        char* as_ = smem + (BUF) * 16384;                               \
        char* bs_ = as_ + 8192;                                         \
        _Pragma("unroll")                                               \
        for (int p_ = 0; p_ < 2; p_++) {                                \
            gload_lds16(Abase + (size_t)(p_ * 16) * (K * 2) + (K0) * 2, \
                        as_ + (wave * 2 + p_) * 1024);                  \
            gload_lds16(Bbase + (size_t)(p_ * 16) * (K * 2) + (K0) * 2, \
                        bs_ + (wave * 2 + p_) * 1024);                  \
        }                                                               \
    } while (0)

__global__ __launch_bounds__(256) void mfma_gemm_kernel(
        const __hip_bfloat16* __restrict__ A,
        const __hip_bfloat16* __restrict__ Bt,
        const float* __restrict__ bias,
        const float* __restrict__ resid,
        float* __restrict__ Cf,
        __hip_bfloat16* __restrict__ Cb,
        int N, int K, int act, int ntile) {
    __shared__ __align__(16) char smem[32768];
    float* Cs = (float*)smem;

    int tid = threadIdx.x;
    int wave = tid >> 6, lane = tid & 63;
    int quad = lane >> 4, l16 = lane & 15;
    int wr = wave >> 1, wc = wave & 1;

    int id = blockIdx.x;
    int slot = id >> 3;
    int mt = (id & 7) * 8 + slot / ntile;
    int nt = slot - (slot / ntile) * ntile;
    int m0 = mt * 128, n0 = nt * 128;

    f32x4 zero = {0.f, 0.f, 0.f, 0.f};
    f32x4 acc00 = zero, acc01 = zero, acc02 = zero, acc03 = zero;
    f32x4 acc10 = zero, acc11 = zero, acc12 = zero, acc13 = zero;
    f32x4 acc20 = zero, acc21 = zero, acc22 = zero, acc23 = zero;
    f32x4 acc30 = zero, acc31 = zero, acc32 = zero, acc33 = zero;

    int srow = lane >> 2;
    int schk = ((lane & 3) + (lane >> 4)) & 3;
    const char* Abase = (const char*)A +
        ((size_t)(m0 + wave * 32 + srow) * K + schk * 8) * 2;
    const char* Bbase = (const char*)Bt +
        ((size_t)(n0 + wave * 32 + srow) * K + schk * 8) * 2;
    int soff = l16 * 4 + ((quad - (l16 >> 2)) & 3);

    int nit = K >> 5;
    STAGE128(0, 0);
    for (int it = 0; it < nit; it++) {
        __syncthreads();
        if (it + 1 < nit) STAGE128((it + 1) << 5, (it + 1) & 1);

        const __hip_bfloat16* as =
            (const __hip_bfloat16*)(smem + (it & 1) * 16384);
        const __hip_bfloat16* bs = as + 4096;

        bf16x8 a0 = *(const bf16x8*)&as[(wr * 4 + 0) * 512 + soff * 8];
        bf16x8 a1 = *(const bf16x8*)&as[(wr * 4 + 1) * 512 + soff * 8];
        bf16x8 a2 = *(const bf16x8*)&as[(wr * 4 + 2) * 512 + soff * 8];
        bf16x8 a3 = *(const bf16x8*)&as[(wr * 4 + 3) * 512 + soff * 8];
        bf16x8 b0 = *(const bf16x8*)&bs[(wc * 4 + 0) * 512 + soff * 8];
        bf16x8 b1 = *(const bf16x8*)&bs[(wc * 4 + 1) * 512 + soff * 8];
        bf16x8 b2 = *(const bf16x8*)&bs[(wc * 4 + 2) * 512 + soff * 8];
        bf16x8 b3 = *(const bf16x8*)&bs[(wc * 4 + 3) * 512 + soff * 8];

        acc00 = MFMA16(a0, b0, acc00); acc01 = MFMA16(a0, b1, acc01);
        acc02 = MFMA16(a0, b2, acc02); acc03 = MFMA16(a0, b3, acc03);
        acc10 = MFMA16(a1, b0, acc10); acc11 = MFMA16(a1, b1, acc11);
        acc12 = MFMA16(a1, b2, acc12); acc13 = MFMA16(a1, b3, acc13);
        acc20 = MFMA16(a2, b0, acc20); acc21 = MFMA16(a2, b1, acc21);
        acc22 = MFMA16(a2, b2, acc22); acc23 = MFMA16(a2, b3, acc23);
        acc30 = MFMA16(a3, b0, acc30); acc31 = MFMA16(a3, b1, acc31);
        acc32 = MFMA16(a3, b2, acc32); acc33 = MFMA16(a3, b3, acc33);
    }

    CHUNK128(0, acc00, acc01, acc02, acc03, acc10, acc11, acc12, acc13);
    CHUNK128(1, acc20, acc21, acc22, acc23, acc30, acc31, acc32, acc33);
    CHUNK128(2, acc00, acc01, acc02, acc03, acc10, acc11, acc12, acc13);
    CHUNK128(3, acc20, acc21, acc22, acc23, acc30, acc31, acc32, acc33);
}

// ---------------------------------------------------------------------------
// MFMA GEMM 64x64 (N=512 outputs): grid 1024 = 4 blocks/CU
// ---------------------------------------------------------------------------
#define PUT64v2(ACC, JJ)                                                \
    do {                                                                \
        int rb_ = (wave & 1) * 16 + quad * 4;                           \
        int cc_ = (JJ) * 16 + l16;                                      \
        Cs[(rb_ + 0) * 68 + cc_] = (ACC)[0];                            \
        Cs[(rb_ + 1) * 68 + cc_] = (ACC)[1];                            \
        Cs[(rb_ + 2) * 68 + cc_] = (ACC)[2];                            \
        Cs[(rb_ + 3) * 68 + cc_] = (ACC)[3];                            \
    } while (0)

#define CHUNK64v2(C)                                                    \
    do {                                                                \
        __syncthreads();                                                \
        if ((wave >> 1) == (C)) {                                       \
            PUT64v2(acc0, 0); PUT64v2(acc1, 1);                         \
            PUT64v2(acc2, 2); PUT64v2(acc3, 3);                         \
        }                                                               \
        __syncthreads();                                                \
        epi_store64(Cs, (C), m0, n0, N, tid, bias, resid, Cf, Cb, act); \
    } while (0)

#define STAGE64v2(K0, BUF)                                              \
    do {                                                                \
        char* as_ = smem + (BUF) * 8192;                                \
        char* bs_ = as_ + 4096;                                         \
        gload_lds16(Abase + (K0) * 2, as_ + wave * 1024);               \
        gload_lds16(Bbase + (K0) * 2, bs_ + wave * 1024);               \
    } while (0)

__global__ __launch_bounds__(256) void mfma_gemm_64_kernel(
        const __hip_bfloat16* __restrict__ A,
        const __hip_bfloat16* __restrict__ Bt,
        const float* __restrict__ bias,
        const float* __restrict__ resid,
        float* __restrict__ Cf,
        __hip_bfloat16* __restrict__ Cb,
        int N, int K, int act, int ntile) {
    __shared__ __align__(16) char smem[16384];
    float* Cs = (float*)smem;

    int tid = threadIdx.x;
    int wave = tid >> 6, lane = tid & 63;
    int quad = lane >> 4, l16 = lane & 15;

    int id = blockIdx.x;
    int slot = id >> 3;
    int mt = (id & 7) * 16 + slot / ntile;
    int nt = slot - (slot / ntile) * ntile;
    int m0 = mt * 64, n0 = nt * 64;

    f32x4 zero = {0.f, 0.f, 0.f, 0.f};
    f32x4 acc0 = zero, acc1 = zero, acc2 = zero, acc3 = zero;

    int srow = lane >> 2;
    int schk = ((lane & 3) + (lane >> 4)) & 3;
    const char* Abase = (const char*)A +
        ((size_t)(m0 + wave * 16 + srow) * K + schk * 8) * 2;
    const char* Bbase = (const char*)Bt +
        ((size_t)(n0 + wave * 16 + srow) * K + schk * 8) * 2;
    int soff = l16 * 4 + ((quad - (l16 >> 2)) & 3);

    int nit = K >> 5;
    STAGE64v2(0, 0);
    for (int it = 0; it < nit; it++) {
        __syncthreads();
        if (it + 1 < nit) STAGE64v2((it + 1) << 5, (it + 1) & 1);

        const __hip_bfloat16* as =
            (const __hip_bfloat16*)(smem + (it & 1) * 8192);
        const __hip_bfloat16* bs = as + 2048;

        bf16x8 a0 = *(const bf16x8*)&as[wave * 512 + soff * 8];
        bf16x8 b0 = *(const bf16x8*)&bs[0 * 512 + soff * 8];
        bf16x8 b1 = *(const bf16x8*)&bs[1 * 512 + soff * 8];
        bf16x8 b2 = *(const bf16x8*)&bs[2 * 512 + soff * 8];
        bf16x8 b3 = *(const bf16x8*)&bs[3 * 512 + soff * 8];

        acc0 = MFMA16(a0, b0, acc0); acc1 = MFMA16(a0, b1, acc1);
        acc2 = MFMA16(a0, b2, acc2); acc3 = MFMA16(a0, b3, acc3);
    }

    CHUNK64v2(0);
    CHUNK64v2(1);
}

// ---------------------------------------------------------------------------
// MFMA flash attention (R13's proven unsplit form: block = 128 q x 1024 keys)
// ---------------------------------------------------------------------------
#define KP 72
__global__ __launch_bounds__(256) void attn_mfma_kernel(
        const __hip_bfloat16* __restrict__ qkv,
        __hip_bfloat16* __restrict__ o) {
    int id = blockIdx.x;
    int slot = id >> 3;
    int bh = (id & 7) * 8 + (slot >> 3);
    int itile = slot & 7;
    int b = bh >> 3, hh = bh & 7;

    int tid = threadIdx.x;
    int wave = tid >> 6, lane = tid & 63;
    int quad = lane >> 4, l16 = lane & 15;
    int i0 = itile * 128;

    __shared__ __align__(16) __hip_bfloat16 Ks[64 * KP];
    __shared__ __align__(16) __hip_bfloat16 Vt[64 * KP];
    __shared__ __align__(16) __hip_bfloat16 Ps[4][16 * KP];

    bf16x8 aq[2][2];
#pragma unroll
    for (int g = 0; g < 2; g++) {
        const __hip_bfloat16* qrow =
            qkv + (size_t)(b * NWIN + i0 + g * 64 + wave * 16 + l16) * 1536 + hh * 64;
        aq[g][0] = *(const bf16x8*)(qrow + quad * 8);
        aq[g][1] = *(const bf16x8*)(qrow + 32 + quad * 8);
    }

    float lp[2][4];
    f32x4 acc[2][4];
    f32x4 zero = {0.f, 0.f, 0.f, 0.f};
#pragma unroll
    for (int g = 0; g < 2; g++)
#pragma unroll
        for (int n = 0; n < 4; n++) { acc[g][n] = zero; lp[g][n] = 0.f; }

    for (int kt = 0; kt < 16; kt++) {
        int k0 = kt * 64;
        __syncthreads();

#pragma unroll
        for (int p = 0; p < 2; p++) {
            int f = p * 256 + tid;
            int r = f >> 3;
            int j = f & 7;
            int c8 = j * 8;
            const __hip_bfloat16* kp =
                qkv + (size_t)(b * NWIN + k0 + r) * 1536 + 512 + hh * 64 + c8;
            *(uint4*)&Ks[r * KP + c8] = *(const uint4*)kp;
            union { uint4 u; __hip_bfloat16 h[8]; } vv;
            vv.u = *(const uint4*)(qkv + (size_t)(b * NWIN + k0 + r) * 1536 +
                                   1024 + hh * 64 + c8);
            int colb = (((r >> 3) ^ j) << 3) + (r & 7);
#pragma unroll
            for (int u = 0; u < 8; u++) Vt[(c8 + u) * KP + colb] = vv.h[u];
        }
        __syncthreads();

        bf16x8 bk[4][2], bv[4][2];
#pragma unroll
        for (int n = 0; n < 4; n++) {
            int key = n * 16 + l16;
            bk[n][0] = *(const bf16x8*)&Ks[key * KP + quad * 8];
            bk[n][1] = *(const bf16x8*)&Ks[key * KP + 32 + quad * 8];
            int d = n * 16 + l16;
            int sw = (d >> 3) & 7;
            bv[n][0] = *(const bf16x8*)&Vt[d * KP + ((quad ^ sw) << 3)];
            bv[n][1] = *(const bf16x8*)&Vt[d * KP + (((quad + 4) ^ sw) << 3)];
        }

#pragma unroll
        for (int g = 0; g < 2; g++) {
            f32x4 s[4];
#pragma unroll
            for (int n = 0; n < 4; n++) {
                f32x4 t = zero;
                t = MFMA16(aq[g][0], bk[n][0], t);
                t = MFMA16(aq[g][1], bk[n][1], t);
                s[n] = t;
            }
#pragma unroll
            for (int r = 0; r < 4; r++) {
                float ls = 0.f;
#pragma unroll
                for (int n = 0; n < 4; n++) {
                    float pv = __expf(s[n][r] * 0.125f);
                    Ps[wave][(quad * 4 + r) * KP + n * 16 + l16] =
                        __float2bfloat16(pv);
                    ls += pv;
                }
                lp[g][r] += ls;
            }
            bf16x8 ap0 = *(const bf16x8*)&Ps[wave][l16 * KP + quad * 8];
            bf16x8 ap1 = *(const bf16x8*)&Ps[wave][l16 * KP + 32 + quad * 8];
#pragma unroll
            for (int n = 0; n < 4; n++) {
                acc[g][n] = MFMA16(ap0, bv[n][0], acc[g][n]);
                acc[g][n] = MFMA16(ap1, bv[n][1], acc[g][n]);
            }
        }
    }

#pragma unroll
    for (int g = 0; g < 2; g++) {
#pragma unroll
        for (int r = 0; r < 4; r++) {
            float ls = lp[g][r];
            ls += __shfl_xor(ls, 1);
            ls += __shfl_xor(ls, 2);
            ls += __shfl_xor(ls, 4);
            ls += __shfl_xor(ls, 8);
            float invl = 1.f / ls;
            int row = i0 + g * 64 + wave * 16 + quad * 4 + r;
#pragma unroll
            for (int n = 0; n < 4; n++) {
                o[(size_t)(b * NWIN + row) * DMODEL + hh * 64 + n * 16 + l16] =
                    __float2bfloat16(acc[g][n][r] * invl);
            }
        }
    }
}

// ---------------------------------------------------------------------------
// Output head (fp32)
// ---------------------------------------------------------------------------
__global__ void out_kernel(const float* __restrict__ x,
                           const int* __restrict__ mask_idx,
                           const float* __restrict__ oln_g,
                           const float* __restrict__ oln_b,
                           const float* __restrict__ W_words,
                           const float* __restrict__ b_words,
                           const float* __restrict__ seq,
                           float* __restrict__ out) {
    int k = blockIdx.x, b = blockIdx.y;
    int idx = mask_idx[b * KMASK + k];
    int t = threadIdx.x;
    const float* row = x + (size_t)(b * NWIN + idx) * DMODEL;
    float v0 = row[t], v1 = row[t + 256];

    __shared__ float red[256], red2[256];
    __shared__ float sh[512];
    __shared__ float part[256];
    __shared__ float lg[32];

    red[t] = v0 + v1;
    red2[t] = v0 * v0 + v1 * v1;
    __syncthreads();
    for (int o = 128; o > 0; o >>= 1) {
        if (t < o) { red[t] += red[t + o]; red2[t] += red2[t + o]; }
        __syncthreads();
    }
    float mean = red[0] * (1.f / 512.f);
    float var = red2[0] * (1.f / 512.f) - mean * mean;
    float rs = rsqrtf(var + 1e-5f);
    sh[t]       = (v0 - mean) * rs * oln_g[t] + oln_b[t];
    sh[t + 256] = (v1 - mean) * rs * oln_g[t + 256] + oln_b[t + 256];
    __syncthreads();

    int c = t & 31, ch = t >> 5;
    float p = 0.f;
    for (int j = ch * 64; j < ch * 64 + 64; j++)
        p += sh[j] * W_words[j * 32 + c];
    part[t] = p;
    __syncthreads();
    if (t < 32) {
        float s = b_words[t];
        for (int u = 0; u < 8; u++) s += part[u * 32 + t];
        lg[t] = s;
    }
    __syncthreads();

    size_t obase = (size_t)(b * KMASK + k) * 32;
    if (t < 32) {
        int g0 = t & ~3;
        float mx = fmaxf(fmaxf(lg[g0], lg[g0 + 1]), fmaxf(lg[g0 + 2], lg[g0 + 3]));
        float s = expf(lg[g0] - mx) + expf(lg[g0 + 1] - mx) +
                  expf(lg[g0 + 2] - mx) + expf(lg[g0 + 3] - mx);
        out[obase + t] = expf(lg[t] - mx) / s;
        out[131072 + obase + t] = seq[(size_t)b * 32768 + (size_t)idx * 32 + t];
    }
}

// ---------------------------------------------------------------------------
extern "C" void kernel_launch(void* const* d_in, const int* in_sizes, int n_in,
                              void* d_out, int out_size, void* d_ws, size_t ws_size,
                              hipStream_t stream) {
    const float* seq      = (const float*)d_in[0];
    const int*   mask_idx = (const int*)d_in[1];
    const float* pos_emb  = (const float*)d_in[2];
    const float* mask_tok = (const float*)d_in[3];
    const float* pln1_g   = (const float*)d_in[4];
    const float* pln1_b   = (const float*)d_in[5];
    const float* W_emb    = (const float*)d_in[6];
    const float* b_emb    = (const float*)d_in[7];
    const float* pln2_g   = (const float*)d_in[8];
    const float* pln2_b   = (const float*)d_in[9];
    const float* aln_g    = (const float*)d_in[10];
    const float* aln_b    = (const float*)d_in[11];
    const float* Wqkv     = (const float*)d_in[12];
    const float* Wo       = (const float*)d_in[13];
    const float* fln_g    = (const float*)d_in[14];
    const float* fln_b    = (const float*)d_in[15];
    const float* Wff1     = (const float*)d_in[16];
    const float* bff1     = (const float*)d_in[17];
    const float* Wff2     = (const float*)d_in[18];
    const float* bff2     = (const float*)d_in[19];
    const float* oln_g    = (const float*)d_in[20];
    const float* oln_b    = (const float*)d_in[21];
    const float* W_words  = (const float*)d_in[22];
    const float* b_words  = (const float*)d_in[23];

    uint8_t* ws = (uint8_t*)d_ws;
    float* x = (float*)ws;
    __hip_bfloat16* qkv_bf = (__hip_bfloat16*)(ws + 16777216);
    __hip_bfloat16* ff_bf  = qkv_bf;
    __hip_bfloat16* h_bf   = (__hip_bfloat16*)(ws + 50331648);
    __hip_bfloat16* o_bf   = (__hip_bfloat16*)(ws + 58720256);
    __hip_bfloat16* wqkv_t = (__hip_bfloat16*)(ws + 67108864);
    __hip_bfloat16* wo_t   = wqkv_t + (size_t)NLAYER * DMODEL * 3 * DMODEL;
    __hip_bfloat16* wff1_t = wo_t   + (size_t)NLAYER * DMODEL * DMODEL;
    __hip_bfloat16* wff2_t = wff1_t + (size_t)NLAYER * DMODEL * FFDIM;

    wconv_kernel<<<dim3(48, 16, NLAYER), 256, 0, stream>>>(Wqkv, wqkv_t, DMODEL, 3 * DMODEL);
    wconv_kernel<<<dim3(16, 16, NLAYER), 256, 0, stream>>>(Wo,   wo_t,   DMODEL, DMODEL);
    wconv_kernel<<<dim3(64, 16, NLAYER), 256, 0, stream>>>(Wff1, wff1_t, DMODEL, FFDIM);
    wconv_kernel<<<dim3(16, 64, NLAYER), 256, 0, stream>>>(Wff2, wff2_t, FFDIM, DMODEL);

    embed_kernel<<<NTOK, 256, 0, stream>>>(seq, pos_emb, pln1_g, pln1_b,
                                           W_emb, b_emb, pln2_g, pln2_b, x);
    mask_scatter_kernel<<<NBATCH * KMASK, 256, 0, stream>>>(mask_idx, mask_tok, pos_emb, x);

    for (int l = 0; l < NLAYER; l++) {
        ln_kernel<<<NTOK, 256, 0, stream>>>(x, h_bf, aln_g + l * DMODEL, aln_b + l * DMODEL);
        mfma_gemm_kernel<<<64 * 12, 256, 0, stream>>>(
            h_bf, wqkv_t + (size_t)l * DMODEL * 3 * DMODEL,
            nullptr, nullptr, nullptr, qkv_bf, 3 * DMODEL, DMODEL, 0, 12);
        attn_mfma_kernel<<<512, 256, 0, stream>>>(qkv_bf, o_bf);
        mfma_gemm_64_kernel<<<128 * 8, 256, 0, stream>>>(
            o_bf, wo_t + (size_t)l * DMODEL * DMODEL,
            nullptr, x, x, nullptr, DMODEL, DMODEL, 0, 8);
        ln_kernel<<<NTOK, 256, 0, stream>>>(x, h_bf, fln_g + l * DMODEL, fln_b + l * DMODEL);
        mfma_gemm_kernel<<<64 * 16, 256, 0, stream>>>(
            h_bf, wff1_t + (size_t)l * DMODEL * FFDIM,
            bff1 + (size_t)l * FFDIM, nullptr, nullptr, ff_bf, FFDIM, DMODEL, 1, 16);
        mfma_gemm_64_kernel<<<128 * 8, 256, 0, stream>>>(
            ff_bf, wff2_t + (size_t)l * FFDIM * DMODEL,
            bff2 + (size_t)l * DMODEL, x, x, nullptr, DMODEL, FFDIM, 0, 8);
    }

    out_kernel<<<dim3(KMASK, NBATCH), 256, 0, stream>>>(
        x, mask_idx, oln_g, oln_b, W_words, b_words, seq, (float*)d_out);
}